// Round 13
// baseline (912.372 us; speedup 1.0000x reference)
//
#include <hip/hip_runtime.h>
#include <hip/hip_bf16.h>
#include <stdint.h>

#define KDIM 512
#define OUT_F 512
#define NTHREADS 1024    // 16 waves: 8M x 2N, wave = 64r x 128c

typedef __attribute__((ext_vector_type(8))) short short8;
typedef __attribute__((ext_vector_type(4))) float floatx4;
typedef __attribute__((ext_vector_type(4))) unsigned int uint32x4;

__device__ __forceinline__ ushort f2bf(float f) {
  uint32_t u = __builtin_bit_cast(uint32_t, f);
  uint32_t r = u + 0x7fffu + ((u >> 16) & 1u);   // RNE bf16
  return (ushort)(r >> 16);
}

typedef const __attribute__((address_space(1))) uint32_t* gas1_u32;
typedef __attribute__((address_space(3))) uint32_t* gas3_u32;

__device__ __forceinline__ void gload_lds16(const void* g, void* l) {
  __builtin_amdgcn_global_load_lds((gas1_u32)g, (gas3_u32)l, 16, 0, 0);
}

#define VMCNT0  asm volatile("s_waitcnt vmcnt(0)" ::: "memory")
#define SBAR    __builtin_amdgcn_s_barrier()

// ---------------------------------------------------------------------------
// Prep: W_eff (512x512) bf16 as [cs(2)][kt(8)][col(256)][k(64)], XOR swizzle
// baked in (G21: linear gload_lds dest, source perm == read perm).
// ---------------------------------------------------------------------------
__global__ void quat_prep_kernel(const float* __restrict__ wr, const float* __restrict__ wi,
                                 const float* __restrict__ wj, const float* __restrict__ wk,
                                 ushort* __restrict__ Bimg) {
  int idx = blockIdx.x * 256 + threadIdx.x;
  if (idx >= 512 * 512) return;
  int o = idx >> 9;        // output-feature index [0,512)
  int c = idx & 511;       // input-feature index [0,512)
  int og = o >> 7, oo = o & 127, cg = c >> 7, cc = c & 127;
  static const int   blkT[16] = {0,1,2,3, 1,0,3,2, 2,3,0,1, 3,2,1,0};
  static const float sgnT[16] = {1.f,-1.f,-1.f,-1.f, 1.f,1.f,1.f,-1.f,
                                 1.f,-1.f,1.f,1.f,   1.f,1.f,-1.f,1.f};
  int sel = og * 4 + cg;
  const float* Ws;
  switch (blkT[sel]) {
    case 0: Ws = wr; break;
    case 1: Ws = wi; break;
    case 2: Ws = wj; break;
    default: Ws = wk; break;
  }
  float v = sgnT[sel] * Ws[oo * 128 + cc];
  int cs = o >> 8, col = o & 255;
  int kt = c >> 6, k = c & 63;
  int dst = ((cs * 8 + kt) * 256 + col) * 64 + (k ^ ((col & 7) << 3));
  Bimg[dst] = f2bf(v);
}

// ---------------------------------------------------------------------------
// GEMM: out[M,512] = X[M,512] * W_eff^T (+bias)
// Block = 512 rows x 256 cols (cs=2). A is NEVER staged in LDS: each lane
// loads its own MFMA A-fragment (2 float4) and converts via
// v_cvt_pk_bf16_f32 — no ds_write/read round-trip, no per-step barrier.
// B = 256 KB staged as two 128 KB K-halves (single LDS buffer, 4 barriers
// per block), M-repeat 4 (wave = 64 rows) -> 0.25 B-reads/MFMA.
// Per-CU vmem traffic 3.5 MB (vs R12's 5.5): X amp 2, B once, out once.
// ---------------------------------------------------------------------------
__global__ void __launch_bounds__(NTHREADS, 1)
quat_gemm_kernel(const float* __restrict__ X, const ushort* __restrict__ Bimg,
                 const float* __restrict__ bias, float* __restrict__ Out) {
  __shared__ __align__(16) ushort Bls[4 * 256 * 64];   // 128 KB (one K-half)

  // 512 blocks = 256 row-groups x 2 cs; cs-pair 8 bids apart -> same XCD L2
  const int bid = blockIdx.x;
  const int wgid = (bid & 7) * 64 + (bid >> 3);
  const int rg = wgid >> 1, cs = wgid & 1;
  const size_t row0 = (size_t)rg * 512;

  const int tid = threadIdx.x, lane = tid & 63, wid = tid >> 6;
  const int lrow = lane & 15;
  const int lg   = lane >> 4;
  const int wm = wid >> 1, wn = wid & 1;     // 8M x 2N wave grid

  const float* Xw = X + (row0 + wm * 64) * KDIM;

  float4 av[2][8];                           // 2-step A prefetch (fragments)

  auto issueA = [&](int s, int p) {          // lane loads its OWN A fragment
#pragma unroll
    for (int sub = 0; sub < 4; ++sub) {
      const float* r = Xw + (size_t)(sub * 16 + lrow) * KDIM + s * 32 + lg * 8;
      av[p][sub * 2]     = *reinterpret_cast<const float4*>(r);
      av[p][sub * 2 + 1] = *reinterpret_cast<const float4*>(r + 4);
    }
  };

  auto cvtA = [&](int p, short8* af) {       // fp32x8 -> bf16x8 in-register
#pragma unroll
    for (int sub = 0; sub < 4; ++sub) {
      float4 a = av[p][2 * sub], b = av[p][2 * sub + 1];
      uint32_t u0, u1, u2, u3;
      asm("v_cvt_pk_bf16_f32 %0, %1, %2" : "=v"(u0) : "v"(a.x), "v"(a.y));
      asm("v_cvt_pk_bf16_f32 %0, %1, %2" : "=v"(u1) : "v"(a.z), "v"(a.w));
      asm("v_cvt_pk_bf16_f32 %0, %1, %2" : "=v"(u2) : "v"(b.x), "v"(b.y));
      asm("v_cvt_pk_bf16_f32 %0, %1, %2" : "=v"(u3) : "v"(b.z), "v"(b.w));
      uint32x4 uu = {u0, u1, u2, u3};
      af[sub] = __builtin_bit_cast(short8, uu);
    }
  };

  auto stageB = [&](int ck) {                // 128 KB: 16 waves x 8 KB
    const ushort* s = Bimg + cs * 131072 + ck * 65536 + wid * 4096 + lane * 8;
    ushort* d = Bls + wid * 4096;
#pragma unroll
    for (int i = 0; i < 8; ++i)
      gload_lds16(s + i * 512, d + i * 512);
  };

  float bv[8];
#pragma unroll
  for (int n = 0; n < 8; ++n) bv[n] = bias[cs * 256 + wn * 128 + n * 16 + lrow];

  floatx4 acc[4][8];
#pragma unroll
  for (int sub = 0; sub < 4; ++sub)
#pragma unroll
    for (int n = 0; n < 8; ++n) acc[sub][n] = {bv[n], bv[n], bv[n], bv[n]};

  // ---- prologue ----
  issueA(0, 0);
  issueA(1, 1);
  stageB(0);
  VMCNT0;
  SBAR;

#pragma unroll
  for (int ck = 0; ck < 2; ++ck) {
    if (ck == 1) {
      SBAR;                 // all waves done reading Bls (K-half 0)
      stageB(1);
      VMCNT0;               // drains gloads (+ ~2-step-old A loads)
      SBAR;
    }
#pragma unroll
    for (int t = 0; t < 8; ++t) {
      const int s = ck * 8 + t;
      short8 af[4];
      cvtA(s & 1, af);                    // auto-vmcnt waits step-s loads only
      if (s <= 13) issueA(s + 2, s & 1);  // refill same buffer, stays in flight

      const ushort* Bt = Bls + (t >> 1) * (256 * 64);
      const int ko = (t & 1) * 32 + lg * 8;
#pragma unroll
      for (int n = 0; n < 8; ++n) {
        int colr = wn * 128 + n * 16 + lrow;
        short8 bf = *reinterpret_cast<const short8*>(
            Bt + colr * 64 + (ko ^ ((colr & 7) << 3)));
#pragma unroll
        for (int sub = 0; sub < 4; ++sub)
          acc[sub][n] = __builtin_amdgcn_mfma_f32_16x16x32_bf16(af[sub], bf, acc[sub][n], 0, 0, 0);
      }
    }
  }

  // ---- epilogue: 64B-half-line adjacent scalar stores (R12's proven order) ----
  float* Ob = Out + (row0 + wm * 64) * OUT_F + cs * 256 + wn * 128;
#pragma unroll
  for (int j = 0; j < 4; ++j) {
#pragma unroll
    for (int sub = 0; sub < 4; ++sub) {
      int r = sub * 16 + lg * 4 + j;
#pragma unroll
      for (int n = 0; n < 8; ++n)
        Ob[(size_t)r * OUT_F + n * 16 + lrow] = acc[sub][n][j];
    }
  }
}

extern "C" void kernel_launch(void* const* d_in, const int* in_sizes, int n_in,
                              void* d_out, int out_size, void* d_ws, size_t ws_size,
                              hipStream_t stream) {
  const float* x    = (const float*)d_in[0];
  const float* wr   = (const float*)d_in[1];
  const float* wi   = (const float*)d_in[2];
  const float* wj   = (const float*)d_in[3];
  const float* wk   = (const float*)d_in[4];
  const float* bias = (const float*)d_in[5];
  float* out = (float*)d_out;
  ushort* Bimg = (ushort*)d_ws;         // 512 KB

  int M = in_sizes[0] / KDIM;           // 131072
  int nwg = (M / 512) * 2;              // 512 blocks

  hipLaunchKernelGGL(quat_prep_kernel, dim3((512 * 512 + 255) / 256), dim3(256), 0, stream,
                     wr, wi, wj, wk, Bimg);
  hipLaunchKernelGGL(quat_gemm_kernel, dim3(nwg), dim3(NTHREADS), 0, stream,
                     x, Bimg, bias, out);
}

// Round 14
// 155.883 us; speedup vs baseline: 5.8529x; 5.8529x over previous
//
#include <hip/hip_runtime.h>
#include <hip/hip_bf16.h>
#include <stdint.h>

#define KDIM 512
#define OUT_F 512
#define BM 128           // rows per block
#define BK 64            // k per step
#define NSTEP 8          // KDIM / BK
#define NTHREADS 1024    // 16 waves, 4M x 4N

typedef __attribute__((ext_vector_type(8))) short short8;
typedef __attribute__((ext_vector_type(4))) float floatx4;

__device__ __forceinline__ ushort f2bf(float f) {
  uint32_t u = __builtin_bit_cast(uint32_t, f);
  uint32_t r = u + 0x7fffu + ((u >> 16) & 1u);   // RNE bf16
  return (ushort)(r >> 16);
}

typedef const __attribute__((address_space(1))) uint32_t* gas1_u32;
typedef __attribute__((address_space(3))) uint32_t* gas3_u32;

__device__ __forceinline__ void gload_lds16(const void* g, void* l) {
  __builtin_amdgcn_global_load_lds((gas1_u32)g, (gas3_u32)l, 16, 0, 0);
}

#define VMCNT2  asm volatile("s_waitcnt vmcnt(2)" ::: "memory")
#define VMCNT0  asm volatile("s_waitcnt vmcnt(0)" ::: "memory")
#define LGKM0   asm volatile("s_waitcnt lgkmcnt(0)" ::: "memory")
#define FENCE   __builtin_amdgcn_sched_barrier(0)
#define SBAR    __builtin_amdgcn_s_barrier()

// ---------------------------------------------------------------------------
// Prep: W_eff (512x512) bf16 as [kt(8)][o(512)][k(64)] with XOR swizzle baked
// in; GEMM stages each 64KB kt-slab linearly via global_load_lds, reads
// swizzled (G21: source perm == read perm, dest linear).
// ---------------------------------------------------------------------------
__global__ void quat_prep_kernel(const float* __restrict__ wr, const float* __restrict__ wi,
                                 const float* __restrict__ wj, const float* __restrict__ wk,
                                 ushort* __restrict__ Bimg) {
  int idx = blockIdx.x * 256 + threadIdx.x;
  if (idx >= 512 * 512) return;
  int o = idx >> 9;        // output-feature index
  int c = idx & 511;       // input-feature index
  int og = o >> 7, oo = o & 127, cg = c >> 7, cc = c & 127;
  static const int   blkT[16] = {0,1,2,3, 1,0,3,2, 2,3,0,1, 3,2,1,0};
  static const float sgnT[16] = {1.f,-1.f,-1.f,-1.f, 1.f,1.f,1.f,-1.f,
                                 1.f,-1.f,1.f,1.f,   1.f,1.f,-1.f,1.f};
  int sel = og * 4 + cg;
  const float* Ws;
  switch (blkT[sel]) {
    case 0: Ws = wr; break;
    case 1: Ws = wi; break;
    case 2: Ws = wj; break;
    default: Ws = wk; break;
  }
  float v = sgnT[sel] * Ws[oo * 128 + cc];
  int kt = c >> 6, k = c & 63;
  int dst = kt * (OUT_F * BK) + o * BK + (k ^ ((o & 7) << 3));
  Bimg[dst] = f2bf(v);
}

// ---------------------------------------------------------------------------
// GEMM: out[M,512] = X[M,512] * W_eff^T (+bias)
// R10 structure: 128 rows x ALL 512 cols, BK=64 counted-vmcnt pipeline.
// ONE change vs R10: epilogue transposes fragments through LDS (reusing Bs,
// 2-way-max bank swizzle) and stores fully-linear float4 (1KB/wave-instr,
// full 128B lines) — removes the 64MB RMW write amplification caused by
// split 64B half-line stores issued far apart.
// ---------------------------------------------------------------------------
__global__ void __launch_bounds__(NTHREADS, 1)
quat_gemm_kernel(const float* __restrict__ X, const ushort* __restrict__ Bimg,
                 const float* __restrict__ bias, float* __restrict__ Out) {
  __shared__ __align__(16) ushort As[2][BM * BK];      // 2 x 16 KB
  __shared__ __align__(16) ushort Bs[2][OUT_F * BK];   // 2 x 64 KB

  const int bid = blockIdx.x;
  const size_t row0 = (size_t)bid * BM;
  const int tid = threadIdx.x, lane = tid & 63, wid = tid >> 6;
  const int lrow = lane & 15;
  const int lg   = lane >> 4;
  const int wm = wid >> 2, wn = wid & 3;     // 4M x 4N wave grid

  const int ar = tid >> 3;                   // A row [0,128)
  const int ac = (tid & 7) * 8;              // A col [0,64) step 8

  float4 av[2][2];                           // 2-deep A prefetch, 8 floats each

  auto issueA = [&](int t, int p) {
    const float* s = X + (row0 + ar) * KDIM + t * BK + ac;
    av[p][0] = *reinterpret_cast<const float4*>(s);
    av[p][1] = *reinterpret_cast<const float4*>(s + 4);
  };
  auto writeA = [&](int p, ushort* Ab) {
    short8 o;
    o[0] = (short)f2bf(av[p][0].x); o[1] = (short)f2bf(av[p][0].y);
    o[2] = (short)f2bf(av[p][0].z); o[3] = (short)f2bf(av[p][0].w);
    o[4] = (short)f2bf(av[p][1].x); o[5] = (short)f2bf(av[p][1].y);
    o[6] = (short)f2bf(av[p][1].z); o[7] = (short)f2bf(av[p][1].w);
    *reinterpret_cast<short8*>(Ab + ar * BK + (ac ^ ((ar & 7) << 3))) = o;
  };
  auto stageB = [&](int t, ushort* Bb) {     // 64KB: 16 waves x 4KB
    const ushort* s = Bimg + t * (OUT_F * BK) + wid * 2048 + lane * 8;
    ushort* d = Bb + wid * 2048;
#pragma unroll
    for (int i = 0; i < 4; ++i)
      gload_lds16(s + i * 512, d + i * 512);
  };

  floatx4 acc[2][8];
#pragma unroll
  for (int m = 0; m < 2; ++m)
#pragma unroll
    for (int n = 0; n < 8; ++n) acc[m][n] = {0.f, 0.f, 0.f, 0.f};

  auto compute = [&](const ushort* Ab, const ushort* Bb) {
#pragma unroll
    for (int kh = 0; kh < 2; ++kh) {
      const int kb = kh * 32 + lg * 8;
      short8 af[2];
#pragma unroll
      for (int m = 0; m < 2; ++m) {
        int row = wm * 32 + m * 16 + lrow;
        af[m] = *reinterpret_cast<const short8*>(Ab + row * BK + (kb ^ ((row & 7) << 3)));
      }
#pragma unroll
      for (int n = 0; n < 8; ++n) {
        int col = wn * 128 + n * 16 + lrow;
        short8 bf = *reinterpret_cast<const short8*>(Bb + col * BK + (kb ^ ((col & 7) << 3)));
        acc[0][n] = __builtin_amdgcn_mfma_f32_16x16x32_bf16(af[0], bf, acc[0][n], 0, 0, 0);
        acc[1][n] = __builtin_amdgcn_mfma_f32_16x16x32_bf16(af[1], bf, acc[1][n], 0, 0, 0);
      }
    }
  };

  // ---- prologue ----
  issueA(0, 0);
  stageB(0, Bs[0]);
  issueA(1, 1);
  writeA(0, As[0]);        // compiler inserts counted wait for A(0) regs
  VMCNT2; FENCE;           // B(0) in LDS; A(1) stays in flight
  LGKM0; SBAR;

  // ---- steady steps t = 0..5: stage B(t+1), prefetch A(t+2) ----
#define STEP_MAIN(T)                                        \
  {                                                         \
    stageB((T) + 1, Bs[((T) & 1) ^ 1]);                     \
    issueA((T) + 2, (T) & 1);                               \
    writeA(((T) + 1) & 1, (ushort*)As[((T) & 1) ^ 1]);      \
    compute(As[(T) & 1], Bs[(T) & 1]);                      \
    VMCNT2; FENCE;                                          \
    LGKM0; SBAR;                                            \
  }
  STEP_MAIN(0) STEP_MAIN(1) STEP_MAIN(2)
  STEP_MAIN(3) STEP_MAIN(4) STEP_MAIN(5)
#undef STEP_MAIN

  // t = 6: stage B(7), no A(8)
  {
    stageB(7, Bs[1]);
    writeA(1, (ushort*)As[1]);
    compute(As[0], Bs[0]);
    VMCNT0; FENCE;
    LGKM0; SBAR;
  }
  // t = 7: compute only
  compute(As[1], Bs[1]);

  // ---- epilogue: LDS transpose (reuse Bs) + fully-linear float4 stores ----
  float bv[8];
#pragma unroll
  for (int n = 0; n < 8; ++n) bv[n] = bias[wn * 128 + n * 16 + lrow];

  float* lds = reinterpret_cast<float*>(&Bs[0][0]);   // 128 KB = 128 rows x 256 f32

#pragma unroll
  for (int pass = 0; pass < 2; ++pass) {
    __syncthreads();                    // pass0: compute done; pass1: readback done
    if ((wn >> 1) == pass) {            // 8 waves deposit cols [pass*256, +256)
#pragma unroll
      for (int m = 0; m < 2; ++m)
#pragma unroll
        for (int n = 0; n < 8; ++n)
#pragma unroll
          for (int j = 0; j < 4; ++j) {
            int row = wm * 32 + m * 16 + lg * 4 + j;
            int cl  = (wn & 1) * 128 + n * 16 + lrow;     // col within pass
            int gs  = (cl >> 2) ^ ((lg & 1) << 2);        // 2-way max (free)
            lds[row * 256 + gs * 4 + (cl & 3)] = acc[m][n][j] + bv[n];
          }
    }
    __syncthreads();
    // all 1024 threads: row-linear float4 readback + store (1KB/wave-instr)
#pragma unroll
    for (int i = 0; i < 8; ++i) {
      int f4  = i * 1024 + tid;         // float4 index in 128x256 image
      int row = f4 >> 6;
      int g   = f4 & 63;
      int gs  = g ^ (((row >> 2) & 1) << 2);
      floatx4 v = *reinterpret_cast<const floatx4*>(lds + row * 256 + gs * 4);
      *reinterpret_cast<floatx4*>(Out + (row0 + row) * OUT_F + pass * 256 + g * 4) = v;
    }
  }
}

extern "C" void kernel_launch(void* const* d_in, const int* in_sizes, int n_in,
                              void* d_out, int out_size, void* d_ws, size_t ws_size,
                              hipStream_t stream) {
  const float* x    = (const float*)d_in[0];
  const float* wr   = (const float*)d_in[1];
  const float* wi   = (const float*)d_in[2];
  const float* wj   = (const float*)d_in[3];
  const float* wk   = (const float*)d_in[4];
  const float* bias = (const float*)d_in[5];
  float* out = (float*)d_out;
  ushort* Bimg = (ushort*)d_ws;         // 512 KB

  int M = in_sizes[0] / KDIM;           // 131072
  int nwg = M / BM;                     // 1024

  hipLaunchKernelGGL(quat_prep_kernel, dim3((512 * 512 + 255) / 256), dim3(256), 0, stream,
                     wr, wi, wj, wk, Bimg);
  hipLaunchKernelGGL(quat_gemm_kernel, dim3(nwg), dim3(NTHREADS), 0, stream,
                     x, Bimg, bias, out);
}

// Round 15
// 150.609 us; speedup vs baseline: 6.0579x; 1.0350x over previous
//
#include <hip/hip_runtime.h>
#include <hip/hip_bf16.h>
#include <stdint.h>

#define KDIM 512
#define OUT_F 512
#define BM 128           // rows per block
#define BK 64            // k per step
#define NSTEP 8          // KDIM / BK
#define NTHREADS 1024    // 16 waves, 4M x 4N

typedef __attribute__((ext_vector_type(8))) short short8;
typedef __attribute__((ext_vector_type(4))) float floatx4;

__device__ __forceinline__ ushort f2bf(float f) {
  uint32_t u = __builtin_bit_cast(uint32_t, f);
  uint32_t r = u + 0x7fffu + ((u >> 16) & 1u);   // RNE bf16
  return (ushort)(r >> 16);
}

typedef const __attribute__((address_space(1))) uint32_t* gas1_u32;
typedef __attribute__((address_space(3))) uint32_t* gas3_u32;

__device__ __forceinline__ void gload_lds16(const void* g, void* l) {
  __builtin_amdgcn_global_load_lds((gas1_u32)g, (gas3_u32)l, 16, 0, 0);
}

#define VMCNT2  asm volatile("s_waitcnt vmcnt(2)" ::: "memory")
#define VMCNT0  asm volatile("s_waitcnt vmcnt(0)" ::: "memory")
#define LGKM0   asm volatile("s_waitcnt lgkmcnt(0)" ::: "memory")
#define FENCE   __builtin_amdgcn_sched_barrier(0)
#define SBAR    __builtin_amdgcn_s_barrier()

// ---------------------------------------------------------------------------
// Prep: W_eff (512x512) bf16 as [kt(8)][o(512)][k(64)] with XOR swizzle baked
// in; GEMM stages each 64KB kt-slab linearly via global_load_lds, reads
// swizzled (G21: source perm == read perm, dest linear).
// ---------------------------------------------------------------------------
__global__ void quat_prep_kernel(const float* __restrict__ wr, const float* __restrict__ wi,
                                 const float* __restrict__ wj, const float* __restrict__ wk,
                                 ushort* __restrict__ Bimg) {
  int idx = blockIdx.x * 256 + threadIdx.x;
  if (idx >= 512 * 512) return;
  int o = idx >> 9;        // output-feature index
  int c = idx & 511;       // input-feature index
  int og = o >> 7, oo = o & 127, cg = c >> 7, cc = c & 127;
  static const int   blkT[16] = {0,1,2,3, 1,0,3,2, 2,3,0,1, 3,2,1,0};
  static const float sgnT[16] = {1.f,-1.f,-1.f,-1.f, 1.f,1.f,1.f,-1.f,
                                 1.f,-1.f,1.f,1.f,   1.f,1.f,-1.f,1.f};
  int sel = og * 4 + cg;
  const float* Ws;
  switch (blkT[sel]) {
    case 0: Ws = wr; break;
    case 1: Ws = wi; break;
    case 2: Ws = wj; break;
    default: Ws = wk; break;
  }
  float v = sgnT[sel] * Ws[oo * 128 + cc];
  int kt = c >> 6, k = c & 63;
  int dst = kt * (OUT_F * BK) + o * BK + (k ^ ((o & 7) << 3));
  Bimg[dst] = f2bf(v);
}

// ---------------------------------------------------------------------------
// GEMM: out[M,512] = X[M,512] * W_eff^T (+bias)
// R10 structure: 128 rows x ALL 512 cols, BK=64 counted-vmcnt pipeline.
// ONE change vs R10: epilogue store order is j-outer/n-INNER (R12's proven
// order) so the 8 64B col-chunks of each output row are issued in adjacent
// instructions -> L2 write-combines full 128B lines -> WRITE_SIZE 326->262MB
// (R12 measured exactly 256MiB with this order; R10's n-outer order split
// line halves ~16 instrs apart -> eviction between halves -> RMW).
// ---------------------------------------------------------------------------
__global__ void __launch_bounds__(NTHREADS, 1)
quat_gemm_kernel(const float* __restrict__ X, const ushort* __restrict__ Bimg,
                 const float* __restrict__ bias, float* __restrict__ Out) {
  __shared__ __align__(16) ushort As[2][BM * BK];      // 2 x 16 KB
  __shared__ __align__(16) ushort Bs[2][OUT_F * BK];   // 2 x 64 KB

  const int bid = blockIdx.x;
  const size_t row0 = (size_t)bid * BM;
  const int tid = threadIdx.x, lane = tid & 63, wid = tid >> 6;
  const int lrow = lane & 15;
  const int lg   = lane >> 4;
  const int wm = wid >> 2, wn = wid & 3;     // 4M x 4N wave grid

  const int ar = tid >> 3;                   // A row [0,128)
  const int ac = (tid & 7) * 8;              // A col [0,64) step 8

  float4 av[2][2];                           // 2-deep A prefetch, 8 floats each

  auto issueA = [&](int t, int p) {
    const float* s = X + (row0 + ar) * KDIM + t * BK + ac;
    av[p][0] = *reinterpret_cast<const float4*>(s);
    av[p][1] = *reinterpret_cast<const float4*>(s + 4);
  };
  auto writeA = [&](int p, ushort* Ab) {
    short8 o;
    o[0] = (short)f2bf(av[p][0].x); o[1] = (short)f2bf(av[p][0].y);
    o[2] = (short)f2bf(av[p][0].z); o[3] = (short)f2bf(av[p][0].w);
    o[4] = (short)f2bf(av[p][1].x); o[5] = (short)f2bf(av[p][1].y);
    o[6] = (short)f2bf(av[p][1].z); o[7] = (short)f2bf(av[p][1].w);
    *reinterpret_cast<short8*>(Ab + ar * BK + (ac ^ ((ar & 7) << 3))) = o;
  };
  auto stageB = [&](int t, ushort* Bb) {     // 64KB: 16 waves x 4KB
    const ushort* s = Bimg + t * (OUT_F * BK) + wid * 2048 + lane * 8;
    ushort* d = Bb + wid * 2048;
#pragma unroll
    for (int i = 0; i < 4; ++i)
      gload_lds16(s + i * 512, d + i * 512);
  };

  floatx4 acc[2][8];
#pragma unroll
  for (int m = 0; m < 2; ++m)
#pragma unroll
    for (int n = 0; n < 8; ++n) acc[m][n] = {0.f, 0.f, 0.f, 0.f};

  auto compute = [&](const ushort* Ab, const ushort* Bb) {
#pragma unroll
    for (int kh = 0; kh < 2; ++kh) {
      const int kb = kh * 32 + lg * 8;
      short8 af[2];
#pragma unroll
      for (int m = 0; m < 2; ++m) {
        int row = wm * 32 + m * 16 + lrow;
        af[m] = *reinterpret_cast<const short8*>(Ab + row * BK + (kb ^ ((row & 7) << 3)));
      }
#pragma unroll
      for (int n = 0; n < 8; ++n) {
        int col = wn * 128 + n * 16 + lrow;
        short8 bf = *reinterpret_cast<const short8*>(Bb + col * BK + (kb ^ ((col & 7) << 3)));
        acc[0][n] = __builtin_amdgcn_mfma_f32_16x16x32_bf16(af[0], bf, acc[0][n], 0, 0, 0);
        acc[1][n] = __builtin_amdgcn_mfma_f32_16x16x32_bf16(af[1], bf, acc[1][n], 0, 0, 0);
      }
    }
  };

  // ---- prologue ----
  issueA(0, 0);
  stageB(0, Bs[0]);
  issueA(1, 1);
  writeA(0, As[0]);        // compiler inserts counted wait for A(0) regs
  VMCNT2; FENCE;           // B(0) in LDS; A(1) stays in flight
  LGKM0; SBAR;

  // ---- steady steps t = 0..5: stage B(t+1), prefetch A(t+2) ----
#define STEP_MAIN(T)                                        \
  {                                                         \
    stageB((T) + 1, Bs[((T) & 1) ^ 1]);                     \
    issueA((T) + 2, (T) & 1);                               \
    writeA(((T) + 1) & 1, (ushort*)As[((T) & 1) ^ 1]);      \
    compute(As[(T) & 1], Bs[(T) & 1]);                      \
    VMCNT2; FENCE;                                          \
    LGKM0; SBAR;                                            \
  }
  STEP_MAIN(0) STEP_MAIN(1) STEP_MAIN(2)
  STEP_MAIN(3) STEP_MAIN(4) STEP_MAIN(5)
#undef STEP_MAIN

  // t = 6: stage B(7), no A(8)
  {
    stageB(7, Bs[1]);
    writeA(1, (ushort*)As[1]);
    compute(As[0], Bs[0]);
    VMCNT0; FENCE;
    LGKM0; SBAR;
  }
  // t = 7: compute only
  compute(As[1], Bs[1]);

  // ---- epilogue: 128x512 fp32, row-adjacent (j-outer/n-inner) stores ----
  float bv[8];
#pragma unroll
  for (int n = 0; n < 8; ++n) bv[n] = bias[wn * 128 + n * 16 + lrow];

  float* Ob = Out + row0 * OUT_F;
#pragma unroll
  for (int m = 0; m < 2; ++m) {
#pragma unroll
    for (int j = 0; j < 4; ++j) {
      int row = wm * 32 + m * 16 + lg * 4 + j;
      float* Orow = Ob + (size_t)row * OUT_F + wn * 128;
#pragma unroll
      for (int n = 0; n < 8; ++n)       // 8 adjacent 64B stores = 4 full lines
        Orow[n * 16 + lrow] = acc[m][n][j] + bv[n];
    }
  }
}

extern "C" void kernel_launch(void* const* d_in, const int* in_sizes, int n_in,
                              void* d_out, int out_size, void* d_ws, size_t ws_size,
                              hipStream_t stream) {
  const float* x    = (const float*)d_in[0];
  const float* wr   = (const float*)d_in[1];
  const float* wi   = (const float*)d_in[2];
  const float* wj   = (const float*)d_in[3];
  const float* wk   = (const float*)d_in[4];
  const float* bias = (const float*)d_in[5];
  float* out = (float*)d_out;
  ushort* Bimg = (ushort*)d_ws;         // 512 KB

  int M = in_sizes[0] / KDIM;           // 131072
  int nwg = M / BM;                     // 1024

  hipLaunchKernelGGL(quat_prep_kernel, dim3((512 * 512 + 255) / 256), dim3(256), 0, stream,
                     wr, wi, wj, wk, Bimg);
  hipLaunchKernelGGL(quat_gemm_kernel, dim3(nwg), dim3(NTHREADS), 0, stream,
                     x, Bimg, bias, out);
}